// Round 12
// baseline (575.039 us; speedup 1.0000x reference)
//
#include <hip/hip_runtime.h>

static constexpr int N = 32768;
static constexpr int K = 4096;
static constexpr int D = 512;

typedef _Float16 f16x8 __attribute__((ext_vector_type(8)));
typedef float f32x4 __attribute__((ext_vector_type(4)));

#define GLD16(GP, LP)                                                   \
  __builtin_amdgcn_global_load_lds(                                     \
      (const __attribute__((address_space(1))) void*)(GP),              \
      (__attribute__((address_space(3))) void*)(LP), 16, 0, 0)

// ---------------------------------------------------------------------------
// fused rowsq + convert (proven): one coalesced pass; hi f16 write +
// bit-exact numpy pairwise sum-of-squares.
// ---------------------------------------------------------------------------
__global__ __launch_bounds__(256) void rowsq_convert_kernel(
    const float* __restrict__ in, float* __restrict__ sqout,
    _Float16* __restrict__ hi, float scale, int rows) {
  __shared__ float ls[8][512];
  int rb = blockIdx.x * 8;
  int tid = threadIdx.x;
#pragma unroll
  for (int g2 = 0; g2 < 2; ++g2) {
    int g = g2 * 256 + tid;
    int r = g >> 6;
    int c8 = (g & 63) * 8;
    const float4* p = (const float4*)(in + (size_t)(rb + r) * D + c8);
    float4 a = p[0], b = p[1];
    float s[8] = {a.x, a.y, a.z, a.w, b.x, b.y, b.z, b.w};
    union { _Float16 h[8]; f16x8 v; } H;
#pragma unroll
    for (int jj = 0; jj < 8; ++jj) {
      H.h[jj] = (_Float16)(s[jj] * scale);
      ls[r][c8 + jj] = s[jj];
    }
    *(f16x8*)(hi + (size_t)(rb + r) * D + c8) = H.v;
  }
  __syncthreads();
  int rr = tid >> 5;
  int l = tid & 31;
  const float* p = &ls[rr][(l >> 3) * 128 + (l & 7)];
  float r = 0.f;
#pragma unroll
  for (int i = 0; i < 16; ++i) {
    float v = p[i * 8];
    r = __fadd_rn(r, __fmul_rn(v, v));
  }
  r = __fadd_rn(r, __shfl_xor(r, 1));
  r = __fadd_rn(r, __shfl_xor(r, 2));
  r = __fadd_rn(r, __shfl_xor(r, 4));
  r = __fadd_rn(r, __shfl_xor(r, 8));
  r = __fadd_rn(r, __shfl_xor(r, 16));
  if (l == 0) sqout[rb + rr] = r;
}

// ---------------------------------------------------------------------------
// transpose cb [K][D] -> cbT [D][K] (for coalesced rescore loads).
// ---------------------------------------------------------------------------
__global__ __launch_bounds__(256) void transpose_kernel(
    const float* __restrict__ in, float* __restrict__ outT) {
  __shared__ float t[32][33];
  int bk = blockIdx.x;  // K/32
  int bd = blockIdx.y;  // D/32
  int tx = threadIdx.x, ty = threadIdx.y;
#pragma unroll
  for (int j = 0; j < 32; j += 8)
    t[ty + j][tx] = in[(size_t)(bk * 32 + ty + j) * D + bd * 32 + tx];
  __syncthreads();
#pragma unroll
  for (int j = 0; j < 32; j += 8)
    outT[(size_t)(bd * 32 + ty + j) * K + bk * 32 + tx] = t[tx][ty + j];
}

// ---------------------------------------------------------------------------
// MFMA distance GEMM + per-block top-2 argmin — round 12.
// Round 11 diagnosis: LDS-read-BW bound (128KB/CU/kt-round @85B/cy = 1540cy
// == measured 1500cy/kt-round). Fix: raise FLOP per LDS byte by growing the
// per-wave tile 64x64 -> 128x64 (8m x 4n frags of 16x16x32):
//   * block = 128 rows x 256 cols, 4 waves side-by-side in N
//   * 12 ds_read_b128 per wave-kt for 2x FLOP (42.7 vs 32 FLOP/B, -33% LDS)
//   * acc 8x4 f32x4 = 128 VGPR (~200 total, launch_bounds(256,2), no spill)
//   * LDS: A 2x8KB + B 2x16KB + 6KB epilogue = 54KB -> 2 blocks/CU
// Sync structure unchanged (proven): 2-buffer, one __syncthreads per kt,
// chunk-XOR swizzle both sides (conflicts==0). MFMA per-output sequence
// identical to rounds 6/11 -> bit-identical distances.
// Grid 4096 = 8 XCD x (4x2 super-grid of 8x8 panel tiles): working set
// 1MB x + 2MB chi = 3MB <= 4MB L2 (round-11 over-fetch fix preserved).
// ---------------------------------------------------------------------------
__global__ __launch_bounds__(256, 2) void mfma_argmin_kernel(
    const _Float16* __restrict__ xh, const _Float16* __restrict__ ch,
    const float* __restrict__ xsq, const float* __restrict__ csq,
    float* __restrict__ pv1, int* __restrict__ pi1, float* __restrict__ pv2) {
  __shared__ __align__(16) _Float16 Ah[2][128 * 32];  // 16 KB
  __shared__ __align__(16) _Float16 Bh[2][256 * 32];  // 32 KB
  __shared__ float mbv1[128][4];
  __shared__ float mbv2[128][4];
  __shared__ int mbi1[128][4];

  int bid = blockIdx.x;              // 4096 blocks
  int xcd = bid & 7, j = bid >> 3;   // j in [0,512)
  int sup = j >> 6, win = j & 63;    // 8 super-tiles of 8x8 blocks
  int rowPanel = xcd * 32 + (sup >> 1) * 8 + (win >> 3);  // [xcd*32, +32)
  int colPanel = (sup & 1) * 8 + (win & 7);               // [0,16)

  int tid = threadIdx.x;
  int w = tid >> 6, l = tid & 63;
  int wcol = w * 64;                 // wave's 64-col slice of the 256
  int rA = l & 15, g = l >> 4;

  const size_t rowBase = (size_t)rowPanel * 128;
  const size_t colBase = (size_t)colPanel * 256;

  f32x4 acc[8][4];
#pragma unroll
  for (int mi = 0; mi < 8; ++mi)
#pragma unroll
    for (int ni = 0; ni < 4; ++ni) acc[mi][ni] = (f32x4)0.f;

  const int r0 = tid >> 2, s0 = tid & 3;
  const int cs = s0 ^ ((r0 >> 1) & 3);          // pre-swizzled source chunk
  const int swz = (g ^ ((rA >> 1) & 3)) * 8;    // read-side swizzle (f16)

  const _Float16* aSrc = xh + (rowBase + r0) * D + cs * 8;
  const _Float16* bSrc = ch + (colBase + r0) * D + cs * 8;

  auto stage = [&](int buf, int kt) {
    const int dOff = kt * 32;
    GLD16(aSrc + dOff, &Ah[buf][(size_t)tid * 8]);
    GLD16(aSrc + dOff + (size_t)64 * D, &Ah[buf][(size_t)(tid + 256) * 8]);
    GLD16(bSrc + dOff, &Bh[buf][(size_t)tid * 8]);
    GLD16(bSrc + dOff + (size_t)64 * D, &Bh[buf][(size_t)(tid + 256) * 8]);
    GLD16(bSrc + dOff + (size_t)128 * D, &Bh[buf][(size_t)(tid + 512) * 8]);
    GLD16(bSrc + dOff + (size_t)192 * D, &Bh[buf][(size_t)(tid + 768) * 8]);
  };

  stage(0, 0);
  int cur = 0;
  for (int kt = 0; kt < 16; ++kt) {
    __syncthreads();                 // drains vmcnt(0)+lgkmcnt(0): buf[cur] ready
    if (kt < 15) stage(cur ^ 1, kt + 1);

    f16x8 bh[4], ah[8];
#pragma unroll
    for (int f = 0; f < 4; ++f)
      bh[f] = *(const f16x8*)&Bh[cur][(wcol + f * 16 + rA) * 32 + swz];
#pragma unroll
    for (int f = 0; f < 8; ++f)
      ah[f] = *(const f16x8*)&Ah[cur][(f * 16 + rA) * 32 + swz];
#pragma unroll
    for (int mi = 0; mi < 8; ++mi)
#pragma unroll
      for (int ni = 0; ni < 4; ++ni)
        acc[mi][ni] =
            __builtin_amdgcn_mfma_f32_16x16x32_f16(ah[mi], bh[ni], acc[mi][ni], 0, 0, 0);
    cur ^= 1;
  }

  // ---- epilogue: distances + per-row top-2 over this wave's 64 cols ----
  const float inv2048 = 1.0f / 2048.0f;
#pragma unroll
  for (int mi = 0; mi < 8; ++mi) {
#pragma unroll
    for (int r = 0; r < 4; ++r) {
      int row_l = mi * 16 + g * 4 + r;
      float xq = xsq[rowBase + row_l];
      float bv1 = 1e30f, bv2 = 1e30f;
      int bi1 = 0x7fffffff;
#pragma unroll
      for (int ni = 0; ni < 4; ++ni) {
        int col = (int)colBase + wcol + ni * 16 + rA;
        float S = acc[mi][ni][r];
        float dsc = (xq - S * inv2048) + csq[col];
        if (dsc < bv1 || (dsc == bv1 && col < bi1)) {
          bv2 = bv1; bv1 = dsc; bi1 = col;
        } else if (dsc < bv2) {
          bv2 = dsc;
        }
      }
#pragma unroll
      for (int m = 1; m < 16; m <<= 1) {
        float ov1 = __shfl_xor(bv1, m);
        int oi1 = __shfl_xor(bi1, m);
        float ov2 = __shfl_xor(bv2, m);
        if (ov1 < bv1 || (ov1 == bv1 && oi1 < bi1)) {
          bv2 = fminf(bv1, ov2); bv1 = ov1; bi1 = oi1;
        } else {
          bv2 = fminf(bv2, ov1);
        }
      }
      if (rA == 0) {
        mbv1[row_l][w] = bv1;
        mbi1[row_l][w] = bi1;
        mbv2[row_l][w] = bv2;
      }
    }
  }
  __syncthreads();
  // merge 4 waves per row (w ascending = col ascending; tie-break keeps lowest)
  if (tid < 128) {
    float bv1 = mbv1[tid][0], bv2 = mbv2[tid][0];
    int bi1 = mbi1[tid][0];
#pragma unroll
    for (int p = 1; p < 4; ++p) {
      float ov1 = mbv1[tid][p];
      int oi1 = mbi1[tid][p];
      float ov2 = mbv2[tid][p];
      if (ov1 < bv1 || (ov1 == bv1 && oi1 < bi1)) {
        bv2 = fminf(bv1, ov2); bv1 = ov1; bi1 = oi1;
      } else {
        bv2 = fminf(bv2, ov1);
      }
    }
    size_t o = (size_t)colPanel * N + (rowBase + tid);
    pv1[o] = bv1; pi1[o] = bi1; pv2[o] = bv2;
  }
}

// ---------------------------------------------------------------------------
// reduce: merge 16 col-panel partials per row -> Z; flag ambiguous rows.
// ---------------------------------------------------------------------------
__global__ __launch_bounds__(256) void reduce_kernel(
    const float* __restrict__ pv1, const int* __restrict__ pi1,
    const float* __restrict__ pv2, float* __restrict__ zout,
    int* __restrict__ ctr, int* __restrict__ list, float eps) {
  int row = blockIdx.x * 256 + threadIdx.x;
  if (row >= N) return;
  float v1 = 1e30f, v2 = 1e30f;
  int i1 = 0x7fffffff;
  for (int jj = 0; jj < 16; ++jj) {
    float ov1 = pv1[(size_t)jj * N + row];
    float ov2 = pv2[(size_t)jj * N + row];
    int oi1 = pi1[(size_t)jj * N + row];
    if (ov1 < v1 || (ov1 == v1 && oi1 < i1)) {
      v2 = fminf(v1, ov2); v1 = ov1; i1 = oi1;
    } else {
      v2 = fminf(v2, ov1);
    }
  }
  zout[row] = (float)i1;
  if (v2 - v1 < eps) {
    int p = atomicAdd(ctr, 1);
    if (p < N) list[p] = row;
  }
}

// ---------------------------------------------------------------------------
// rescore (LDS-staged, proven round-6): exact fp32 argmin for flagged rows.
// ---------------------------------------------------------------------------
static constexpr int RT_ROWS = 16;
static constexpr int RT_PANELS = 8;
static constexpr int CHUNK_D = 8;

__global__ __launch_bounds__(256) void rescore_tiled_kernel(
    const float* __restrict__ x, const float* __restrict__ cbT,
    const float* __restrict__ xsq, const float* __restrict__ csq,
    const int* __restrict__ ctr, const int* __restrict__ list,
    float* __restrict__ prv, int* __restrict__ pri) {
  __shared__ float xs[RT_ROWS][D + 4];
  __shared__ __align__(16) float cbs[2][CHUNK_D][512];
  int cnt = *ctr;
  if (cnt > N) cnt = N;
  int nTiles = (cnt + RT_ROWS - 1) / RT_ROWS;
  int nItems = nTiles * RT_PANELS;
  int tid = threadIdx.x;
  int ty = tid >> 4;
  int tx = tid & 15;

  for (int item = blockIdx.x; item < nItems; item += gridDim.x) {
    int tileIdx = item >> 3;
    int panel = item & 7;
    int base = tileIdx * RT_ROWS;
    int colPanel = panel * 512;
    __syncthreads();

    for (int i = tid; i < RT_ROWS * (D / 4); i += 256) {
      int r = i >> 7;
      int d4 = i & 127;
      int fi = base + r;
      int row = list[fi < cnt ? fi : 0];
      ((float4*)&xs[r][0])[d4] = ((const float4*)(x + (size_t)row * D))[d4];
    }

    auto stageCb = [&](int buf, int chk) {
      const float* src = cbT + (size_t)(chk * CHUNK_D) * K + colPanel;
#pragma unroll
      for (int it = 0; it < 4; ++it) {
        int f = it * 256 + tid;
        int dd = f >> 7, c4 = f & 127;
        GLD16(src + (size_t)dd * K + c4 * 4, &cbs[buf][0][0] + (size_t)f * 4);
      }
    };

    stageCb(0, 0);
    float acc[32];
#pragma unroll
    for (int c = 0; c < 32; ++c) acc[c] = 0.f;

    int cur = 0;
    for (int chk = 0; chk < D / CHUNK_D; ++chk) {
      __syncthreads();
      if (chk < D / CHUNK_D - 1) stageCb(cur ^ 1, chk + 1);
#pragma unroll
      for (int dd = 0; dd < CHUNK_D; ++dd) {
        float xa = xs[ty][chk * CHUNK_D + dd];
        const float4* cp = (const float4*)&cbs[cur][dd][0];
#pragma unroll
        for (int jj = 0; jj < 8; ++jj) {
          float4 v = cp[tx + jj * 16];
          acc[jj * 4 + 0] = fmaf(xa, v.x, acc[jj * 4 + 0]);
          acc[jj * 4 + 1] = fmaf(xa, v.y, acc[jj * 4 + 1]);
          acc[jj * 4 + 2] = fmaf(xa, v.z, acc[jj * 4 + 2]);
          acc[jj * 4 + 3] = fmaf(xa, v.w, acc[jj * 4 + 3]);
        }
      }
      cur ^= 1;
    }

    int fi = base + ty;
    int row = list[fi < cnt ? fi : 0];
    float xq = xsq[row];
    float bv = 1e30f;
    int bi = 0x7fffffff;
#pragma unroll
    for (int jj = 0; jj < 8; ++jj) {
#pragma unroll
      for (int q = 0; q < 4; ++q) {
        int col = colPanel + jj * 64 + tx * 4 + q;
        float a = acc[jj * 4 + q];
        float two = __fadd_rn(a, a);
        float t = __fsub_rn(xq, two);
        float dsc = __fadd_rn(t, csq[col]);
        if (dsc < bv || (dsc == bv && col < bi)) { bv = dsc; bi = col; }
      }
    }
#pragma unroll
    for (int m = 1; m < 16; m <<= 1) {
      float ov = __shfl_xor(bv, m);
      int oi = __shfl_xor(bi, m);
      if (ov < bv || (ov == bv && oi < bi)) { bv = ov; bi = oi; }
    }
    if (tx == 0 && fi < cnt) {
      prv[(size_t)fi * RT_PANELS + panel] = bv;
      pri[(size_t)fi * RT_PANELS + panel] = bi;
    }
  }
}

__global__ __launch_bounds__(256) void rescore_reduce_kernel(
    const float* __restrict__ prv, const int* __restrict__ pri,
    const int* __restrict__ ctr, const int* __restrict__ list,
    float* __restrict__ zout) {
  int cnt = *ctr;
  if (cnt > N) cnt = N;
  for (int fi = blockIdx.x * 256 + threadIdx.x; fi < cnt;
       fi += gridDim.x * 256) {
    float bv = 1e30f;
    int bi = 0x7fffffff;
#pragma unroll
    for (int p = 0; p < RT_PANELS; ++p) {
      float v = prv[(size_t)fi * RT_PANELS + p];
      int i = pri[(size_t)fi * RT_PANELS + p];
      if (v < bv || (v == bv && i < bi)) { bv = v; bi = i; }
    }
    zout[list[fi]] = (float)bi;
  }
}

// ---------------------------------------------------------------------------
// Fallback fp32 argmin (used only if ws is too small).
// ---------------------------------------------------------------------------
static constexpr int BM = 64;
static constexpr int BKc = 128;
static constexpr int BD = 32;

__global__ __launch_bounds__(256) void argmin_fp32_kernel(
    const float* __restrict__ x, const float* __restrict__ cb,
    const float* __restrict__ xsq, const float* __restrict__ csq,
    float* __restrict__ zout) {
  __shared__ float xs[BD][BM];
  __shared__ float cs_[BD][BKc];
  __shared__ float mv[BM][16];
  __shared__ int mi[BM][16];

  int tid = threadIdx.x;
  int tx = tid & 15;
  int ty = tid >> 4;
  int row0 = blockIdx.x * BM;

  float bestv[4];
  int besti[4];
  float xsqr[4];
#pragma unroll
  for (int i = 0; i < 4; ++i) {
    bestv[i] = 3.4e38f;
    besti[i] = 0x7fffffff;
    xsqr[i] = xsq[row0 + ty * 4 + i];
  }

  for (int kt = 0; kt < K; kt += BKc) {
    float acc[4][8];
#pragma unroll
    for (int i = 0; i < 4; ++i)
#pragma unroll
      for (int jj = 0; jj < 8; ++jj) acc[i][jj] = 0.f;

    for (int dt = 0; dt < D; dt += BD) {
      __syncthreads();
      {
        int r = tid >> 2, d0 = (tid & 3) * 8;
        const float* src = x + (size_t)(row0 + r) * D + dt + d0;
        float4 v0 = *(const float4*)(src);
        float4 v1 = *(const float4*)(src + 4);
        xs[d0 + 0][r] = v0.x; xs[d0 + 1][r] = v0.y;
        xs[d0 + 2][r] = v0.z; xs[d0 + 3][r] = v0.w;
        xs[d0 + 4][r] = v1.x; xs[d0 + 5][r] = v1.y;
        xs[d0 + 6][r] = v1.z; xs[d0 + 7][r] = v1.w;
      }
      {
        int kk = tid >> 1, d0 = (tid & 1) * 16;
        const float* src = cb + (size_t)(kt + kk) * D + dt + d0;
        float4 v0 = *(const float4*)(src);
        float4 v1 = *(const float4*)(src + 4);
        float4 v2 = *(const float4*)(src + 8);
        float4 v3 = *(const float4*)(src + 12);
        cs_[d0 + 0][kk] = v0.x;  cs_[d0 + 1][kk] = v0.y;
        cs_[d0 + 2][kk] = v0.z;  cs_[d0 + 3][kk] = v0.w;
        cs_[d0 + 4][kk] = v1.x;  cs_[d0 + 5][kk] = v1.y;
        cs_[d0 + 6][kk] = v1.z;  cs_[d0 + 7][kk] = v1.w;
        cs_[d0 + 8][kk] = v2.x;  cs_[d0 + 9][kk] = v2.y;
        cs_[d0 + 10][kk] = v2.z; cs_[d0 + 11][kk] = v2.w;
        cs_[d0 + 12][kk] = v3.x; cs_[d0 + 13][kk] = v3.y;
        cs_[d0 + 14][kk] = v3.z; cs_[d0 + 15][kk] = v3.w;
      }
      __syncthreads();
#pragma unroll 4
      for (int d = 0; d < BD; ++d) {
        float xa[4], cv[8];
        *(float4*)&xa[0] = *(const float4*)&xs[d][ty * 4];
        *(float4*)&cv[0] = *(const float4*)&cs_[d][tx * 8];
        *(float4*)&cv[4] = *(const float4*)&cs_[d][tx * 8 + 4];
#pragma unroll
        for (int i = 0; i < 4; ++i)
#pragma unroll
          for (int jj = 0; jj < 8; ++jj)
            acc[i][jj] = fmaf(xa[i], cv[jj], acc[i][jj]);
      }
    }

#pragma unroll
    for (int jj = 0; jj < 8; ++jj) {
      int k = kt + tx * 8 + jj;
      float cq = csq[k];
#pragma unroll
      for (int i = 0; i < 4; ++i) {
        float two = __fadd_rn(acc[i][jj], acc[i][jj]);
        float t = __fsub_rn(xsqr[i], two);
        float dsc = __fadd_rn(t, cq);
        if (dsc < bestv[i]) { bestv[i] = dsc; besti[i] = k; }
      }
    }
  }

  __syncthreads();
#pragma unroll
  for (int i = 0; i < 4; ++i) {
    mv[ty * 4 + i][tx] = bestv[i];
    mi[ty * 4 + i][tx] = besti[i];
  }
  __syncthreads();
  if (tid < BM) {
    float bv = mv[tid][0];
    int bi = mi[tid][0];
#pragma unroll
    for (int t = 1; t < 16; ++t) {
      float v = mv[tid][t];
      int ii = mi[tid][t];
      if (v < bv || (v == bv && ii < bi)) { bv = v; bi = ii; }
    }
    zout[row0 + tid] = (float)bi;
  }
}

// ---------------------------------------------------------------------------
// gather + loss.
// ---------------------------------------------------------------------------
__global__ __launch_bounds__(256) void gather_kernel(
    const float* __restrict__ x, const float* __restrict__ cb,
    const float* __restrict__ zf, float* __restrict__ qout,
    float* __restrict__ partial) {
  __shared__ float red[256];
  const size_t TOT4 = (size_t)N * D / 4;
  size_t t0 = (size_t)blockIdx.x * 256 + threadIdx.x;
  float lsum = 0.f;
  for (size_t f = t0; f < TOT4; f += (size_t)2048 * 256) {
    int n = (int)(f >> 7);
    int d4 = (int)(f & 127);
    int z = (int)zf[n];
    float4 xv = ((const float4*)x)[f];
    float4 qv = *(const float4*)(cb + (size_t)z * D + d4 * 4);
    float dx0 = __fsub_rn(qv.x, xv.x);
    float dx1 = __fsub_rn(qv.y, xv.y);
    float dx2 = __fsub_rn(qv.z, xv.z);
    float dx3 = __fsub_rn(qv.w, xv.w);
    float4 o;
    o.x = __fadd_rn(xv.x, dx0);
    o.y = __fadd_rn(xv.y, dx1);
    o.z = __fadd_rn(xv.z, dx2);
    o.w = __fadd_rn(xv.w, dx3);
    ((float4*)qout)[f] = o;
    lsum += dx0 * dx0 + dx1 * dx1 + dx2 * dx2 + dx3 * dx3;
  }
  red[threadIdx.x] = lsum;
  __syncthreads();
  for (int s = 128; s > 0; s >>= 1) {
    if (threadIdx.x < s) red[threadIdx.x] += red[threadIdx.x + s];
    __syncthreads();
  }
  if (threadIdx.x == 0) partial[blockIdx.x] = red[0];
}

__global__ __launch_bounds__(256) void loss_kernel(const float* __restrict__ partial,
                                                   float* __restrict__ loss_out) {
  __shared__ float red[256];
  float s = 0.f;
  for (int i = threadIdx.x; i < 2048; i += 256) s += partial[i];
  red[threadIdx.x] = s;
  __syncthreads();
  for (int k = 128; k > 0; k >>= 1) {
    if (threadIdx.x < k) red[threadIdx.x] += red[threadIdx.x + k];
    __syncthreads();
  }
  if (threadIdx.x == 0) {
    float m = red[0] / (float)((size_t)N * D);
    loss_out[0] = m;
    loss_out[1] = m;
  }
}

// ---------------------------------------------------------------------------
// workspace layout (bytes).  f16/transposed scratch lives in the q-output
// region (64 MB, fully overwritten by gather at the end):
//   qout+0      : xhi  (N*D f16, 32 MB)
//   qout+32 MB  : cbT  (D*K f32,  8 MB)
//   qout+40 MB  : chi  (K*D f16,  4 MB)
// ---------------------------------------------------------------------------
static constexpr size_t OFF_XSQ = 0;                         // N*4
static constexpr size_t OFF_CSQ = 131072;                    // K*4
static constexpr size_t OFF_PART = 147456;                   // 2048*4
static constexpr size_t OFF_CTR = 155648;                    // 256
static constexpr size_t OFF_LIST = 155904;                   // N*4
static constexpr size_t OFF_PV1 = 286976;                    // N*16*4
static constexpr size_t OFF_PI1 = OFF_PV1 + 2097152;
static constexpr size_t OFF_PV2 = OFF_PI1 + 2097152;
static constexpr size_t OFF_PRV = OFF_PV2 + 2097152;         // N*8*4
static constexpr size_t OFF_PRI = OFF_PRV + 1048576;
static constexpr size_t WS_REQ = OFF_PRI + 1048576;          // ~8.6 MB

extern "C" void kernel_launch(void* const* d_in, const int* in_sizes, int n_in,
                              void* d_out, int out_size, void* d_ws, size_t ws_size,
                              hipStream_t stream) {
  const float* x = (const float*)d_in[0];
  const float* cb = (const float*)d_in[1];
  float* out = (float*)d_out;

  float* zout = out;
  float* qout = out + N;
  float* lout = out + N + (size_t)N * D;

  char* ws = (char*)d_ws;
  float* xsq = (float*)(ws + OFF_XSQ);
  float* csq = (float*)(ws + OFF_CSQ);
  float* partial = (float*)(ws + OFF_PART);

  // q-region scratch
  _Float16* xhi = (_Float16*)qout;
  float* cbT = (float*)((char*)qout + (size_t)N * D * 2);
  _Float16* chi = (_Float16*)((char*)cbT + (size_t)D * K * 4);

  rowsq_convert_kernel<<<dim3(N / 8), dim3(256), 0, stream>>>(x, xsq, xhi,
                                                              16.0f, N);
  rowsq_convert_kernel<<<dim3(K / 8), dim3(256), 0, stream>>>(cb, csq, chi,
                                                              256.0f, K);

  if (ws_size >= WS_REQ) {
    int* ctr = (int*)(ws + OFF_CTR);
    int* list = (int*)(ws + OFF_LIST);
    float* pv1 = (float*)(ws + OFF_PV1);
    int* pi1 = (int*)(ws + OFF_PI1);
    float* pv2 = (float*)(ws + OFF_PV2);
    float* prv = (float*)(ws + OFF_PRV);
    int* pri = (int*)(ws + OFF_PRI);

    transpose_kernel<<<dim3(K / 32, D / 32), dim3(32, 8), 0, stream>>>(cb, cbT);
    hipMemsetAsync(ctr, 0, sizeof(int), stream);
    mfma_argmin_kernel<<<dim3((N / 128) * (K / 256)), dim3(256), 0, stream>>>(
        xhi, chi, xsq, csq, pv1, pi1, pv2);
    reduce_kernel<<<dim3(N / 256), dim3(256), 0, stream>>>(pv1, pi1, pv2, zout,
                                                           ctr, list, 0.02f);
    rescore_tiled_kernel<<<dim3(1024), dim3(256), 0, stream>>>(
        x, cbT, xsq, csq, ctr, list, prv, pri);
    rescore_reduce_kernel<<<dim3(128), dim3(256), 0, stream>>>(prv, pri, ctr,
                                                               list, zout);
  } else {
    argmin_fp32_kernel<<<dim3(N / BM), dim3(256), 0, stream>>>(x, cb, xsq, csq,
                                                               zout);
  }

  gather_kernel<<<dim3(2048), dim3(256), 0, stream>>>(x, cb, zout, qout, partial);
  loss_kernel<<<dim3(1), dim3(256), 0, stream>>>(partial, lout);
}

// Round 13
// 531.501 us; speedup vs baseline: 1.0819x; 1.0819x over previous
//
#include <hip/hip_runtime.h>

static constexpr int N = 32768;
static constexpr int K = 4096;
static constexpr int D = 512;

typedef _Float16 f16x8 __attribute__((ext_vector_type(8)));
typedef float f32x4 __attribute__((ext_vector_type(4)));

#define GLD16(GP, LP)                                                   \
  __builtin_amdgcn_global_load_lds(                                     \
      (const __attribute__((address_space(1))) void*)(GP),              \
      (__attribute__((address_space(3))) void*)(LP), 16, 0, 0)

// ---------------------------------------------------------------------------
// Fused preprocessing (one dispatch):
//   blocks [0,4096)        : x rowsq + f16-hi convert (8 rows each)
//   blocks [4096,4608)     : cb rowsq + f16-hi convert
//   blocks [4608,6656)     : cb transpose -> cbT (for rescore)
// rowsq arithmetic is the bit-exact numpy pairwise tree (proven round 1/9).
// LDS stash sub-padded [8][4][132]: same elements/values, read-phase bank
// aliasing 8-way -> ~2-way (free).
// ---------------------------------------------------------------------------
__global__ __launch_bounds__(256) void preprocess_kernel(
    const float* __restrict__ x, const float* __restrict__ cb,
    float* __restrict__ xsq, float* __restrict__ csq,
    _Float16* __restrict__ xhi, _Float16* __restrict__ chi,
    float* __restrict__ cbT) {
  __shared__ __align__(16) char lsraw[8 * 4 * 132 * 4];
  int bid = blockIdx.x;
  int tid = threadIdx.x;

  if (bid < 4096 + 512) {
    // ---- rowsq + convert ----
    float (*ls)[4][132] = (float(*)[4][132])lsraw;
    const float* in;
    float* sqout;
    _Float16* hi;
    float scale;
    int rb;
    if (bid < 4096) {
      in = x; sqout = xsq; hi = xhi; scale = 16.0f; rb = bid * 8;
    } else {
      in = cb; sqout = csq; hi = chi; scale = 256.0f; rb = (bid - 4096) * 8;
    }
#pragma unroll
    for (int g2 = 0; g2 < 2; ++g2) {
      int g = g2 * 256 + tid;
      int r = g >> 6;
      int c8 = (g & 63) * 8;
      const float4* p = (const float4*)(in + (size_t)(rb + r) * D + c8);
      float4 a = p[0], b = p[1];
      float s[8] = {a.x, a.y, a.z, a.w, b.x, b.y, b.z, b.w};
      union { _Float16 h[8]; f16x8 v; } H;
      int blk = c8 >> 7, col = c8 & 127;
#pragma unroll
      for (int jj = 0; jj < 8; ++jj) {
        H.h[jj] = (_Float16)(s[jj] * scale);
        ls[r][blk][col + jj] = s[jj];
      }
      *(f16x8*)(hi + (size_t)(rb + r) * D + c8) = H.v;
    }
    __syncthreads();
    int rr = tid >> 5;
    int l = tid & 31;
    const float* p = &ls[rr][l >> 3][l & 7];
    float r = 0.f;
#pragma unroll
    for (int i = 0; i < 16; ++i) {
      float v = p[i * 8];
      r = __fadd_rn(r, __fmul_rn(v, v));
    }
    r = __fadd_rn(r, __shfl_xor(r, 1));
    r = __fadd_rn(r, __shfl_xor(r, 2));
    r = __fadd_rn(r, __shfl_xor(r, 4));
    r = __fadd_rn(r, __shfl_xor(r, 8));
    r = __fadd_rn(r, __shfl_xor(r, 16));
    if (l == 0) sqout[rb + rr] = r;
  } else {
    // ---- transpose cb [K][D] -> cbT [D][K] ----
    float (*t)[33] = (float(*)[33])lsraw;
    int tb = bid - 4608;           // 0..2047 = (K/32)*(D/32)
    int bk = tb >> 4;              // 0..127
    int bd = tb & 15;              // 0..15
    int tx = tid & 31, ty = tid >> 5;
#pragma unroll
    for (int j = 0; j < 32; j += 8)
      t[ty + j][tx] = cb[(size_t)(bk * 32 + ty + j) * D + bd * 32 + tx];
    __syncthreads();
#pragma unroll
    for (int j = 0; j < 32; j += 8)
      cbT[(size_t)(bd * 32 + ty + j) * K + bk * 32 + tx] = t[tx][ty + j];
  }
}

// ---------------------------------------------------------------------------
// MFMA distance GEMM + per-block top-2 argmin — round-11 kernel VERBATIM
// (best measured: 320us, MfmaUtil 18.6, FETCH 82MB, conflicts 0).
// hi-only, 128x128, 4 waves 2x2, BK=32, 2-buffer LDS, one __syncthreads
// per kt, chunk-XOR swizzle both sides, 8x8 super-tile L2 ordering.
// ---------------------------------------------------------------------------
__global__ __launch_bounds__(256) void mfma_argmin_kernel(
    const _Float16* __restrict__ xh, const _Float16* __restrict__ ch,
    const float* __restrict__ xsq, const float* __restrict__ csq,
    float* __restrict__ pv1, int* __restrict__ pi1, float* __restrict__ pv2) {
  __shared__ __align__(16) _Float16 Ah[2][128 * 32];
  __shared__ __align__(16) _Float16 Bh[2][128 * 32];
  __shared__ float mbv1[128];
  __shared__ int mbi1[128];
  __shared__ float mbv2[128];

  int bid = blockIdx.x;
  int xcd = bid & 7, j = bid >> 3;
  int sup = j >> 6, win = j & 63;
  int rowPanel = xcd * 32 + (sup >> 2) * 8 + (win >> 3);
  int colPanel = (sup & 3) * 8 + (win & 7);

  int tid = threadIdx.x;
  int w = tid >> 6, l = tid & 63;
  int wr = w >> 1, wc = w & 1;
  int wrow = wr * 64, wcol = wc * 64;
  int rA = l & 15, g = l >> 4;

  const size_t rowBase = (size_t)rowPanel * 128;
  const size_t colBase = (size_t)colPanel * 128;

  f32x4 acc[4][4];
#pragma unroll
  for (int mi = 0; mi < 4; ++mi)
#pragma unroll
    for (int ni = 0; ni < 4; ++ni) acc[mi][ni] = (f32x4)0.f;

  const int r0 = tid >> 2, s0 = tid & 3;
  const int cs = s0 ^ ((r0 >> 1) & 3);          // pre-swizzled source chunk
  const int swz = (g ^ ((rA >> 1) & 3)) * 8;    // read-side swizzle (f16)

  const _Float16* aSrc = xh + (rowBase + r0) * D + cs * 8;
  const _Float16* bSrc = ch + (colBase + r0) * D + cs * 8;

  auto stage = [&](int buf, int kt) {
    const int dOff = kt * 32;
    GLD16(aSrc + dOff, &Ah[buf][(size_t)tid * 8]);
    GLD16(aSrc + dOff + (size_t)64 * D, &Ah[buf][(size_t)(tid + 256) * 8]);
    GLD16(bSrc + dOff, &Bh[buf][(size_t)tid * 8]);
    GLD16(bSrc + dOff + (size_t)64 * D, &Bh[buf][(size_t)(tid + 256) * 8]);
  };

  stage(0, 0);
  int cur = 0;
  for (int kt = 0; kt < 16; ++kt) {
    __syncthreads();                 // drains vmcnt(0)+lgkmcnt(0): buf[cur] ready
    if (kt < 15) stage(cur ^ 1, kt + 1);

    f16x8 ah[4], bh[4];
#pragma unroll
    for (int f = 0; f < 4; ++f) {
      ah[f] = *(const f16x8*)&Ah[cur][(wrow + f * 16 + rA) * 32 + swz];
      bh[f] = *(const f16x8*)&Bh[cur][(wcol + f * 16 + rA) * 32 + swz];
    }
#pragma unroll
    for (int mi = 0; mi < 4; ++mi)
#pragma unroll
      for (int ni = 0; ni < 4; ++ni)
        acc[mi][ni] =
            __builtin_amdgcn_mfma_f32_16x16x32_f16(ah[mi], bh[ni], acc[mi][ni], 0, 0, 0);
    cur ^= 1;
  }

  const float inv2048 = 1.0f / 2048.0f;
  float fv1[4][4], fv2[4][4];
  int fi1[4][4];
#pragma unroll
  for (int mi = 0; mi < 4; ++mi) {
#pragma unroll
    for (int r = 0; r < 4; ++r) {
      int row_l = wrow + mi * 16 + g * 4 + r;
      float xq = xsq[rowBase + row_l];
      float bv1 = 1e30f, bv2 = 1e30f;
      int bi1 = 0x7fffffff;
#pragma unroll
      for (int ni = 0; ni < 4; ++ni) {
        int col = (int)colBase + wcol + ni * 16 + rA;
        float S = acc[mi][ni][r];
        float dsc = (xq - S * inv2048) + csq[col];
        if (dsc < bv1 || (dsc == bv1 && col < bi1)) {
          bv2 = bv1; bv1 = dsc; bi1 = col;
        } else if (dsc < bv2) {
          bv2 = dsc;
        }
      }
#pragma unroll
      for (int m = 1; m < 16; m <<= 1) {
        float ov1 = __shfl_xor(bv1, m);
        int oi1 = __shfl_xor(bi1, m);
        float ov2 = __shfl_xor(bv2, m);
        if (ov1 < bv1 || (ov1 == bv1 && oi1 < bi1)) {
          bv2 = fminf(bv1, ov2); bv1 = ov1; bi1 = oi1;
        } else {
          bv2 = fminf(bv2, ov1);
        }
      }
      fv1[mi][r] = bv1; fv2[mi][r] = bv2; fi1[mi][r] = bi1;
      if (wc == 1 && rA == 0) {
        mbv1[row_l] = bv1; mbi1[row_l] = bi1; mbv2[row_l] = bv2;
      }
    }
  }
  __syncthreads();
  if (wc == 0 && rA == 0) {
#pragma unroll
    for (int mi = 0; mi < 4; ++mi) {
#pragma unroll
      for (int r = 0; r < 4; ++r) {
        int row_l = wrow + mi * 16 + g * 4 + r;
        float bv1 = fv1[mi][r], bv2 = fv2[mi][r];
        int bi1 = fi1[mi][r];
        float ov1 = mbv1[row_l];
        int oi1 = mbi1[row_l];
        float ov2 = mbv2[row_l];
        if (ov1 < bv1 || (ov1 == bv1 && oi1 < bi1)) {
          bv2 = fminf(bv1, ov2); bv1 = ov1; bi1 = oi1;
        } else {
          bv2 = fminf(bv2, ov1);
        }
        size_t o = (size_t)colPanel * N + (rowBase + row_l);
        pv1[o] = bv1; pi1[o] = bi1; pv2[o] = bv2;
      }
    }
  }
}

// ---------------------------------------------------------------------------
// reduce: merge 32 col-panel partials per row -> Z; flag ambiguous rows.
// ---------------------------------------------------------------------------
__global__ __launch_bounds__(256) void reduce_kernel(
    const float* __restrict__ pv1, const int* __restrict__ pi1,
    const float* __restrict__ pv2, float* __restrict__ zout,
    int* __restrict__ ctr, int* __restrict__ list, float eps) {
  int row = blockIdx.x * 256 + threadIdx.x;
  if (row >= N) return;
  float v1 = 1e30f, v2 = 1e30f;
  int i1 = 0x7fffffff;
  for (int jj = 0; jj < 32; ++jj) {
    float ov1 = pv1[(size_t)jj * N + row];
    float ov2 = pv2[(size_t)jj * N + row];
    int oi1 = pi1[(size_t)jj * N + row];
    if (ov1 < v1 || (ov1 == v1 && oi1 < i1)) {
      v2 = fminf(v1, ov2); v1 = ov1; i1 = oi1;
    } else {
      v2 = fminf(v2, ov1);
    }
  }
  zout[row] = (float)i1;
  if (v2 - v1 < eps) {
    int p = atomicAdd(ctr, 1);
    if (p < N) list[p] = row;
  }
}

// ---------------------------------------------------------------------------
// rescore (LDS-staged, proven round-6): exact fp32 argmin for flagged rows.
// ---------------------------------------------------------------------------
static constexpr int RT_ROWS = 16;
static constexpr int RT_PANELS = 8;
static constexpr int CHUNK_D = 8;

__global__ __launch_bounds__(256) void rescore_tiled_kernel(
    const float* __restrict__ x, const float* __restrict__ cbT,
    const float* __restrict__ xsq, const float* __restrict__ csq,
    const int* __restrict__ ctr, const int* __restrict__ list,
    float* __restrict__ prv, int* __restrict__ pri) {
  __shared__ float xs[RT_ROWS][D + 4];
  __shared__ __align__(16) float cbs[2][CHUNK_D][512];
  int cnt = *ctr;
  if (cnt > N) cnt = N;
  int nTiles = (cnt + RT_ROWS - 1) / RT_ROWS;
  int nItems = nTiles * RT_PANELS;
  int tid = threadIdx.x;
  int ty = tid >> 4;
  int tx = tid & 15;

  for (int item = blockIdx.x; item < nItems; item += gridDim.x) {
    int tileIdx = item >> 3;
    int panel = item & 7;
    int base = tileIdx * RT_ROWS;
    int colPanel = panel * 512;
    __syncthreads();

    for (int i = tid; i < RT_ROWS * (D / 4); i += 256) {
      int r = i >> 7;
      int d4 = i & 127;
      int fi = base + r;
      int row = list[fi < cnt ? fi : 0];
      ((float4*)&xs[r][0])[d4] = ((const float4*)(x + (size_t)row * D))[d4];
    }

    auto stageCb = [&](int buf, int chk) {
      const float* src = cbT + (size_t)(chk * CHUNK_D) * K + colPanel;
#pragma unroll
      for (int it = 0; it < 4; ++it) {
        int f = it * 256 + tid;
        int dd = f >> 7, c4 = f & 127;
        GLD16(src + (size_t)dd * K + c4 * 4, &cbs[buf][0][0] + (size_t)f * 4);
      }
    };

    stageCb(0, 0);
    float acc[32];
#pragma unroll
    for (int c = 0; c < 32; ++c) acc[c] = 0.f;

    int cur = 0;
    for (int chk = 0; chk < D / CHUNK_D; ++chk) {
      __syncthreads();
      if (chk < D / CHUNK_D - 1) stageCb(cur ^ 1, chk + 1);
#pragma unroll
      for (int dd = 0; dd < CHUNK_D; ++dd) {
        float xa = xs[ty][chk * CHUNK_D + dd];
        const float4* cp = (const float4*)&cbs[cur][dd][0];
#pragma unroll
        for (int jj = 0; jj < 8; ++jj) {
          float4 v = cp[tx + jj * 16];
          acc[jj * 4 + 0] = fmaf(xa, v.x, acc[jj * 4 + 0]);
          acc[jj * 4 + 1] = fmaf(xa, v.y, acc[jj * 4 + 1]);
          acc[jj * 4 + 2] = fmaf(xa, v.z, acc[jj * 4 + 2]);
          acc[jj * 4 + 3] = fmaf(xa, v.w, acc[jj * 4 + 3]);
        }
      }
      cur ^= 1;
    }

    int fi = base + ty;
    int row = list[fi < cnt ? fi : 0];
    float xq = xsq[row];
    float bv = 1e30f;
    int bi = 0x7fffffff;
#pragma unroll
    for (int jj = 0; jj < 8; ++jj) {
#pragma unroll
      for (int q = 0; q < 4; ++q) {
        int col = colPanel + jj * 64 + tx * 4 + q;
        float a = acc[jj * 4 + q];
        float two = __fadd_rn(a, a);
        float t = __fsub_rn(xq, two);
        float dsc = __fadd_rn(t, csq[col]);
        if (dsc < bv || (dsc == bv && col < bi)) { bv = dsc; bi = col; }
      }
    }
#pragma unroll
    for (int m = 1; m < 16; m <<= 1) {
      float ov = __shfl_xor(bv, m);
      int oi = __shfl_xor(bi, m);
      if (ov < bv || (ov == bv && oi < bi)) { bv = ov; bi = oi; }
    }
    if (tx == 0 && fi < cnt) {
      prv[(size_t)fi * RT_PANELS + panel] = bv;
      pri[(size_t)fi * RT_PANELS + panel] = bi;
    }
  }
}

__global__ __launch_bounds__(256) void rescore_reduce_kernel(
    const float* __restrict__ prv, const int* __restrict__ pri,
    const int* __restrict__ ctr, const int* __restrict__ list,
    float* __restrict__ zout) {
  int cnt = *ctr;
  if (cnt > N) cnt = N;
  for (int fi = blockIdx.x * 256 + threadIdx.x; fi < cnt;
       fi += gridDim.x * 256) {
    float bv = 1e30f;
    int bi = 0x7fffffff;
#pragma unroll
    for (int p = 0; p < RT_PANELS; ++p) {
      float v = prv[(size_t)fi * RT_PANELS + p];
      int i = pri[(size_t)fi * RT_PANELS + p];
      if (v < bv || (v == bv && i < bi)) { bv = v; bi = i; }
    }
    zout[list[fi]] = (float)bi;
  }
}

// ---------------------------------------------------------------------------
// Fallback fp32 argmin (used only if ws is too small).
// ---------------------------------------------------------------------------
static constexpr int BM = 64;
static constexpr int BKc = 128;
static constexpr int BD = 32;

__global__ __launch_bounds__(256) void argmin_fp32_kernel(
    const float* __restrict__ x, const float* __restrict__ cb,
    const float* __restrict__ xsq, const float* __restrict__ csq,
    float* __restrict__ zout) {
  __shared__ float xs[BD][BM];
  __shared__ float cs_[BD][BKc];
  __shared__ float mv[BM][16];
  __shared__ int mi[BM][16];

  int tid = threadIdx.x;
  int tx = tid & 15;
  int ty = tid >> 4;
  int row0 = blockIdx.x * BM;

  float bestv[4];
  int besti[4];
  float xsqr[4];
#pragma unroll
  for (int i = 0; i < 4; ++i) {
    bestv[i] = 3.4e38f;
    besti[i] = 0x7fffffff;
    xsqr[i] = xsq[row0 + ty * 4 + i];
  }

  for (int kt = 0; kt < K; kt += BKc) {
    float acc[4][8];
#pragma unroll
    for (int i = 0; i < 4; ++i)
#pragma unroll
      for (int jj = 0; jj < 8; ++jj) acc[i][jj] = 0.f;

    for (int dt = 0; dt < D; dt += BD) {
      __syncthreads();
      {
        int r = tid >> 2, d0 = (tid & 3) * 8;
        const float* src = x + (size_t)(row0 + r) * D + dt + d0;
        float4 v0 = *(const float4*)(src);
        float4 v1 = *(const float4*)(src + 4);
        xs[d0 + 0][r] = v0.x; xs[d0 + 1][r] = v0.y;
        xs[d0 + 2][r] = v0.z; xs[d0 + 3][r] = v0.w;
        xs[d0 + 4][r] = v1.x; xs[d0 + 5][r] = v1.y;
        xs[d0 + 6][r] = v1.z; xs[d0 + 7][r] = v1.w;
      }
      {
        int kk = tid >> 1, d0 = (tid & 1) * 16;
        const float* src = cb + (size_t)(kt + kk) * D + dt + d0;
        float4 v0 = *(const float4*)(src);
        float4 v1 = *(const float4*)(src + 4);
        float4 v2 = *(const float4*)(src + 8);
        float4 v3 = *(const float4*)(src + 12);
        cs_[d0 + 0][kk] = v0.x;  cs_[d0 + 1][kk] = v0.y;
        cs_[d0 + 2][kk] = v0.z;  cs_[d0 + 3][kk] = v0.w;
        cs_[d0 + 4][kk] = v1.x;  cs_[d0 + 5][kk] = v1.y;
        cs_[d0 + 6][kk] = v1.z;  cs_[d0 + 7][kk] = v1.w;
        cs_[d0 + 8][kk] = v2.x;  cs_[d0 + 9][kk] = v2.y;
        cs_[d0 + 10][kk] = v2.z; cs_[d0 + 11][kk] = v2.w;
        cs_[d0 + 12][kk] = v3.x; cs_[d0 + 13][kk] = v3.y;
        cs_[d0 + 14][kk] = v3.z; cs_[d0 + 15][kk] = v3.w;
      }
      __syncthreads();
#pragma unroll 4
      for (int d = 0; d < BD; ++d) {
        float xa[4], cv[8];
        *(float4*)&xa[0] = *(const float4*)&xs[d][ty * 4];
        *(float4*)&cv[0] = *(const float4*)&cs_[d][tx * 8];
        *(float4*)&cv[4] = *(const float4*)&cs_[d][tx * 8 + 4];
#pragma unroll
        for (int i = 0; i < 4; ++i)
#pragma unroll
          for (int jj = 0; jj < 8; ++jj)
            acc[i][jj] = fmaf(xa[i], cv[jj], acc[i][jj]);
      }
    }

#pragma unroll
    for (int jj = 0; jj < 8; ++jj) {
      int k = kt + tx * 8 + jj;
      float cq = csq[k];
#pragma unroll
      for (int i = 0; i < 4; ++i) {
        float two = __fadd_rn(acc[i][jj], acc[i][jj]);
        float t = __fsub_rn(xsqr[i], two);
        float dsc = __fadd_rn(t, cq);
        if (dsc < bestv[i]) { bestv[i] = dsc; besti[i] = k; }
      }
    }
  }

  __syncthreads();
#pragma unroll
  for (int i = 0; i < 4; ++i) {
    mv[ty * 4 + i][tx] = bestv[i];
    mi[ty * 4 + i][tx] = besti[i];
  }
  __syncthreads();
  if (tid < BM) {
    float bv = mv[tid][0];
    int bi = mi[tid][0];
#pragma unroll
    for (int t = 1; t < 16; ++t) {
      float v = mv[tid][t];
      int ii = mi[tid][t];
      if (v < bv || (v == bv && ii < bi)) { bv = v; bi = ii; }
    }
    zout[row0 + tid] = (float)bi;
  }
}

// ---------------------------------------------------------------------------
// gather + loss.
// ---------------------------------------------------------------------------
__global__ __launch_bounds__(256) void gather_kernel(
    const float* __restrict__ x, const float* __restrict__ cb,
    const float* __restrict__ zf, float* __restrict__ qout,
    float* __restrict__ partial) {
  __shared__ float red[256];
  const size_t TOT4 = (size_t)N * D / 4;
  size_t t0 = (size_t)blockIdx.x * 256 + threadIdx.x;
  float lsum = 0.f;
  for (size_t f = t0; f < TOT4; f += (size_t)2048 * 256) {
    int n = (int)(f >> 7);
    int d4 = (int)(f & 127);
    int z = (int)zf[n];
    float4 xv = ((const float4*)x)[f];
    float4 qv = *(const float4*)(cb + (size_t)z * D + d4 * 4);
    float dx0 = __fsub_rn(qv.x, xv.x);
    float dx1 = __fsub_rn(qv.y, xv.y);
    float dx2 = __fsub_rn(qv.z, xv.z);
    float dx3 = __fsub_rn(qv.w, xv.w);
    float4 o;
    o.x = __fadd_rn(xv.x, dx0);
    o.y = __fadd_rn(xv.y, dx1);
    o.z = __fadd_rn(xv.z, dx2);
    o.w = __fadd_rn(xv.w, dx3);
    ((float4*)qout)[f] = o;
    lsum += dx0 * dx0 + dx1 * dx1 + dx2 * dx2 + dx3 * dx3;
  }
  red[threadIdx.x] = lsum;
  __syncthreads();
  for (int s = 128; s > 0; s >>= 1) {
    if (threadIdx.x < s) red[threadIdx.x] += red[threadIdx.x + s];
    __syncthreads();
  }
  if (threadIdx.x == 0) partial[blockIdx.x] = red[0];
}

__global__ __launch_bounds__(256) void loss_kernel(const float* __restrict__ partial,
                                                   float* __restrict__ loss_out) {
  __shared__ float red[256];
  float s = 0.f;
  for (int i = threadIdx.x; i < 2048; i += 256) s += partial[i];
  red[threadIdx.x] = s;
  __syncthreads();
  for (int k = 128; k > 0; k >>= 1) {
    if (threadIdx.x < k) red[threadIdx.x] += red[threadIdx.x + k];
    __syncthreads();
  }
  if (threadIdx.x == 0) {
    float m = red[0] / (float)((size_t)N * D);
    loss_out[0] = m;
    loss_out[1] = m;
  }
}

// ---------------------------------------------------------------------------
// workspace layout (bytes).  f16/transposed scratch lives in the q-output
// region (64 MB, fully overwritten by gather at the end):
//   qout+0      : xhi  (N*D f16, 32 MB)
//   qout+32 MB  : cbT  (D*K f32,  8 MB)
//   qout+40 MB  : chi  (K*D f16,  4 MB)
// ---------------------------------------------------------------------------
static constexpr size_t OFF_XSQ = 0;                         // N*4
static constexpr size_t OFF_CSQ = 131072;                    // K*4
static constexpr size_t OFF_PART = 147456;                   // 2048*4
static constexpr size_t OFF_CTR = 155648;                    // 256
static constexpr size_t OFF_LIST = 155904;                   // N*4
static constexpr size_t OFF_PV1 = 286976;                    // N*32*4
static constexpr size_t OFF_PI1 = OFF_PV1 + 4194304;
static constexpr size_t OFF_PV2 = OFF_PI1 + 4194304;
static constexpr size_t OFF_PRV = OFF_PV2 + 4194304;         // N*8*4
static constexpr size_t OFF_PRI = OFF_PRV + 1048576;
static constexpr size_t WS_REQ = OFF_PRI + 1048576;          // ~14.3 MB

extern "C" void kernel_launch(void* const* d_in, const int* in_sizes, int n_in,
                              void* d_out, int out_size, void* d_ws, size_t ws_size,
                              hipStream_t stream) {
  const float* x = (const float*)d_in[0];
  const float* cb = (const float*)d_in[1];
  float* out = (float*)d_out;

  float* zout = out;
  float* qout = out + N;
  float* lout = out + N + (size_t)N * D;

  char* ws = (char*)d_ws;
  float* xsq = (float*)(ws + OFF_XSQ);
  float* csq = (float*)(ws + OFF_CSQ);
  float* partial = (float*)(ws + OFF_PART);

  // q-region scratch
  _Float16* xhi = (_Float16*)qout;
  float* cbT = (float*)((char*)qout + (size_t)N * D * 2);
  _Float16* chi = (_Float16*)((char*)cbT + (size_t)D * K * 4);

  if (ws_size >= WS_REQ) {
    int* ctr = (int*)(ws + OFF_CTR);
    int* list = (int*)(ws + OFF_LIST);
    float* pv1 = (float*)(ws + OFF_PV1);
    int* pi1 = (int*)(ws + OFF_PI1);
    float* pv2 = (float*)(ws + OFF_PV2);
    float* prv = (float*)(ws + OFF_PRV);
    int* pri = (int*)(ws + OFF_PRI);

    preprocess_kernel<<<dim3(4096 + 512 + 2048), dim3(256), 0, stream>>>(
        x, cb, xsq, csq, xhi, chi, cbT);
    hipMemsetAsync(ctr, 0, sizeof(int), stream);
    mfma_argmin_kernel<<<dim3((N / 128) * (K / 128)), dim3(256), 0, stream>>>(
        xhi, chi, xsq, csq, pv1, pi1, pv2);
    reduce_kernel<<<dim3(N / 256), dim3(256), 0, stream>>>(pv1, pi1, pv2, zout,
                                                           ctr, list, 0.02f);
    rescore_tiled_kernel<<<dim3(1024), dim3(256), 0, stream>>>(
        x, cbT, xsq, csq, ctr, list, prv, pri);
    rescore_reduce_kernel<<<dim3(128), dim3(256), 0, stream>>>(prv, pri, ctr,
                                                               list, zout);
  } else {
    preprocess_kernel<<<dim3(4096 + 512 + 2048), dim3(256), 0, stream>>>(
        x, cb, xsq, csq, xhi, chi, cbT);
    argmin_fp32_kernel<<<dim3(N / BM), dim3(256), 0, stream>>>(x, cb, xsq, csq,
                                                               zout);
  }

  gather_kernel<<<dim3(2048), dim3(256), 0, stream>>>(x, cb, zout, qout, partial);
  loss_kernel<<<dim3(1), dim3(256), 0, stream>>>(partial, lout);
}